// Round 6
// baseline (12030.083 us; speedup 1.0000x reference)
//
#include <hip/hip_runtime.h>
#include <cmath>

#define BATCH 256
#define TSTEPS 512
#define NDIM 256
#define WASH 64
#define TOUT (TSTEPS - WASH)   /* 448 */
#define NB 8                   /* batch rows per team */
#define CS 8                   /* column-split blocks per team */
#define NTEAM (BATCH / NB)     /* 32 */
#define NBLK (NTEAM * CS)      /* 256 */
#define NT 1024

/* workspace layout (floats) */
#define SBUF_SZ (3 * BATCH * 512)            /* state triple buffer [3][256][512] */
#define RING_OFF SBUF_SZ
#define RING_SZ (4 * NTEAM * CS * 16)        /* logit partials [4][32][8][16] */
#define CTR_OFF (RING_OFF + RING_SZ)
#define CTR_SZ (NTEAM * 32)                  /* one 128B-padded counter line per team */

__global__ void init_kernel(float* ws) {
    const int n0 = BATCH * 512;              /* sbuf slot 0 must start zero */
    const int n1 = RING_SZ + CTR_SZ;
    for (int i = blockIdx.x * blockDim.x + threadIdx.x; i < n0 + n1;
         i += gridDim.x * blockDim.x) {
        float* p = (i < n0) ? (ws + i) : (ws + RING_OFF + (i - n0));
        __hip_atomic_store(p, 0.f, __ATOMIC_RELAXED, __HIP_MEMORY_SCOPE_AGENT);
    }
}

__global__ void __launch_bounds__(NT, 4)
loop_kernel(const int* __restrict__ settings, const float* __restrict__ noiseA,
            const float* __restrict__ noiseB, const float* __restrict__ WinA,
            const float* __restrict__ WrecA, const float* __restrict__ WinB,
            const float* __restrict__ WrecB, const float* __restrict__ Wx,
            const float* __restrict__ bg, const float* __restrict__ Wout,
            const float* __restrict__ bout, float* __restrict__ out, float* ws)
{
    __shared__ float xbuf[516][8];    /* x transposed [k][row], 4-float sub-block swizzled */
    __shared__ float sT[512][8];      /* raw state transposed, same swizzle */
    __shared__ float partA[16][64][9];/* gx k-split partials (stride 9) */
    __shared__ float partB[16][64][9];/* reservoir k-split partials */
    __shared__ float hzT[32][9];      /* sigmoid(z) [own h-col][row] */
    __shared__ float hnT[32][9];      /* tanh(n) */
    __shared__ float bitsf[8][2];
    __shared__ float dly[8][2];       /* reduced delayed logits (t-2) */

    const int tid  = threadIdx.x;
    const int cs   = blockIdx.x >> 5;
    const int team = blockIdx.x & 31;
    const int r0   = team * NB;

    float*    ring    = ws + RING_OFF;
    unsigned* ctrline = (unsigned*)(ws + CTR_OFF) + team * 32;  /* dwords [0..7] used */

    /* GEMM mapping: tid = kq*64 + rh*32 + c2 */
    const int kq = tid >> 6;
    const int rh = (tid >> 5) & 1;
    const int c2 = tid & 31;
    const float* wxp0 = Wx + ((c2 < 16) ? (cs * 32 + 2 * c2)
                                        : (512 + cs * 32 + 2 * (c2 - 16)));
    const int side  = cs >> 2;               /* 0 = A, 1 = B */
    const int scol0 = (cs & 3) * 64;
    const float* wrp0 = (side ? WrecB : WrecA) + (scol0 + 2 * c2);
    const float* wins = side ? WinB : WinA;

    /* register-resident reservoir weights: 16 k x 2 cols */
    float2 w_s[16];
    #pragma unroll
    for (int k = 0; k < 16; ++k)
        w_s[k] = *(const float2*)(wrp0 + (size_t)(kq * 16 + k) * 256);

    /* X mapping */
    const int xk = tid & 511;
    const int xh = tid >> 9;

    /* Gr / Sr constants */
    float biasg = 0.f, win0r = 0.f, win1r = 0.f;
    if (tid < 512) {
        const int oc = tid & 63;
        biasg = bg[(oc < 32) ? (cs * 32 + oc) : (512 + cs * 32 + (oc - 32))];
        win0r = wins[scol0 + oc];
        win1r = wins[NDIM + scol0 + oc];
    }
    /* logits mapping: wave wv = (r, j), lanes < 32 hold own h-cols */
    const int lane = tid & 63;
    const int wv = tid >> 6;
    const int lr = wv >> 1, lj = wv & 1;
    const float woreg = (lane < 32) ? Wout[(cs * 32 + lane) * 2 + lj] : 0.f;

    float* out0 = out;
    float* out1 = out + (size_t)BATCH * TOUT;
    float* out2 = out + (size_t)2 * BATCH * TOUT;

    for (int t = 0; t < TSTEPS; ++t) {
        const int sb_r = t % 3, sb_w = (t + 1) % 3;

        /* ---- P0a: noise prefetch (independent of remote state) ---- */
        float nz[4];
        {
            const float* np_ = (xk < 256)
                ? (noiseA + (size_t)r0 * TSTEPS * NDIM + (size_t)t * NDIM + xk)
                : (noiseB + (size_t)r0 * TSTEPS * NDIM + (size_t)t * NDIM + (xk - 256));
            #pragma unroll
            for (int q = 0; q < 4; ++q)
                nz[q] = np_[(size_t)(xh * 4 + q) * TSTEPS * NDIM];
        }
        if (tid >= 16 && tid < 32) {          /* delayed-logit reduce: ring(t-2) was
                                                 made visible by last step's wait */
            const int r = (tid - 16) >> 1, j = tid & 1;
            float s = (t >= 2) ? bout[j] : 0.f;
            #pragma unroll
            for (int q = 0; q < CS; ++q)
                s += __hip_atomic_load(
                    &ring[((((size_t)((t + 2) & 3)) * NTEAM + team) * CS + q) * 16 + r * 2 + j],
                    __ATOMIC_RELAXED, __HIP_MEMORY_SCOPE_AGENT);
            dly[r][j] = s;
            if (cs == 0 && t - 2 >= WASH) {
                const float sg = (s > 0.f) ? 1.f : ((s < 0.f) ? -1.f : 0.f);
                (j ? out1 : out0)[(size_t)(r0 + r) * TOUT + (t - 2 - WASH)] = sg;
            }
        } else if (tid < 16) {                /* bits + spins (+ out2 by cs0) */
            const int r = tid >> 1, j = tid & 1;
            const float bit = (float)settings[((size_t)(r0 + r) * TSTEPS + t) * 2 + j];
            bitsf[r][j] = bit;
            xbuf[512 + j][r] = 2.f * bit - 1.f;   /* (k>>2)&1 == 0 here */
            if (cs == 0 && t >= WASH)
                out2[((size_t)(r0 + r) * TOUT + (t - WASH)) * 2 + j] = bit;
        }

        /* ---- P0b: wave-0 wait on the team counter line (MALL-pinned via RMW).
                lane i polls dword i of ONE 64B line; RMW'd lines poll cheaply
                (r3 evidence) unlike store-published flags (r4/r5 evidence). ---- */
        if (t > 0 && wv == 0 && lane < CS) {
            long guard = 0;
            while (__hip_atomic_load(&ctrline[lane], __ATOMIC_RELAXED,
                                     __HIP_MEMORY_SCOPE_AGENT) < (unsigned)t) {
                __builtin_amdgcn_s_sleep(8);
                if (++guard > 300000L) break;   /* hang insurance */
            }
            (void)__hip_atomic_load(&ctrline[lane], __ATOMIC_ACQUIRE,
                                    __HIP_MEMORY_SCOPE_AGENT);
        }
        __syncthreads();   /* releases all waves once every producer counter >= t */

        /* ---- P0c: state gather -> xbuf / sT (swizzled) ---- */
        {
            const float* srow = ws + (size_t)sb_r * (BATCH * 512) + xk;
            float u[4], v[4];
            #pragma unroll
            for (int q = 0; q < 4; ++q) {
                u[q] = __hip_atomic_load(srow + (size_t)(r0 + xh * 4 + q) * 512,
                                         __ATOMIC_RELAXED, __HIP_MEMORY_SCOPE_AGENT);
                v[q] = u[q] + nz[q];
            }
            const int sw = 4 * (xh ^ ((xk >> 2) & 1));
            *(float4*)&xbuf[xk][sw] = make_float4(v[0], v[1], v[2], v[3]);
            *(float4*)&sT[xk][sw]   = make_float4(u[0], u[1], u[2], u[3]);
        }
        __syncthreads();

        /* ---- P1: Gp -> partA, Sp -> partB (back-to-back, one sync) ---- */
        {
            const int kbeg = kq * 32;
            const int kend = (kq == 15) ? 514 : (kbeg + 32);
            float a00=0,a01=0,a10=0,a11=0,a20=0,a21=0,a30=0,a31=0;
            const float* wp = wxp0 + (size_t)kbeg * 768;
            #pragma unroll 4
            for (int k = kbeg; k < kend; ++k, wp += 768) {
                const float2 w  = *(const float2*)wp;
                const float4 xv = *(const float4*)&xbuf[k][4 * (rh ^ ((k >> 2) & 1))];
                a00 = fmaf(xv.x, w.x, a00); a01 = fmaf(xv.x, w.y, a01);
                a10 = fmaf(xv.y, w.x, a10); a11 = fmaf(xv.y, w.y, a11);
                a20 = fmaf(xv.z, w.x, a20); a21 = fmaf(xv.z, w.y, a21);
                a30 = fmaf(xv.w, w.x, a30); a31 = fmaf(xv.w, w.y, a31);
            }
            float* pb = &partA[kq][rh * 32 + c2][0];
            pb[0] = a00; pb[1] = a10; pb[2] = a20; pb[3] = a30;
            pb[4] = a01; pb[5] = a11; pb[6] = a21; pb[7] = a31;
        }
        {
            const int kb = kq * 16;
            float a00=0,a01=0,a10=0,a11=0,a20=0,a21=0,a30=0,a31=0;
            #pragma unroll
            for (int k = 0; k < 16; ++k) {
                const float2 w = w_s[k];
                const int k2 = side * 256 + kb + k;
                const float4 sv = *(const float4*)&sT[k2][4 * (rh ^ ((k2 >> 2) & 1))];
                a00 = fmaf(sv.x, w.x, a00); a01 = fmaf(sv.x, w.y, a01);
                a10 = fmaf(sv.y, w.x, a10); a11 = fmaf(sv.y, w.y, a11);
                a20 = fmaf(sv.z, w.x, a20); a21 = fmaf(sv.z, w.y, a21);
                a30 = fmaf(sv.w, w.x, a30); a31 = fmaf(sv.w, w.y, a31);
            }
            float* pb = &partB[kq][rh * 32 + c2][0];
            pb[0] = a00; pb[1] = a10; pb[2] = a20; pb[3] = a30;
            pb[4] = a01; pb[5] = a11; pb[6] = a21; pb[7] = a31;
        }
        __syncthreads();

        /* ---- P2: Gr reduce + activation ---- */
        if (tid < 512) {
            const int rr = tid >> 6, oc = tid & 63;
            const int g = (rr >> 2) * 32 + (oc >> 1);
            const int i = (oc & 1) * 4 + (rr & 3);
            float e = biasg;
            #pragma unroll
            for (int q = 0; q < 16; ++q) e += partA[q][g][i];
            if (oc < 32) hzT[oc][rr] = 1.f / (1.f + expf(-e));
            else         hnT[oc - 32][rr] = tanhf(e);
        }
        __syncthreads();

        /* ---- P3: logit partial + Sr + counter publish ---- */
        {
            float pl = 0.f;
            if (lane < 32)
                pl = (1.f - hzT[lane][lr]) * hnT[lane][lr] * woreg;
            #pragma unroll
            for (int s = 16; s; s >>= 1) pl += __shfl_down(pl, s, 64);
            if (lane == 0)
                __hip_atomic_store(
                    &ring[((((size_t)(t & 3)) * NTEAM + team) * CS + cs) * 16 + wv],
                    pl, __ATOMIC_RELAXED, __HIP_MEMORY_SCOPE_AGENT);
        }
        if (tid < 512) {
            const int rr = tid >> 6, sc = tid & 63;
            const int g = (rr >> 2) * 32 + (sc >> 1);
            const int i = (sc & 1) * 4 + (rr & 3);
            float e = 0.f;
            #pragma unroll
            for (int q = 0; q < 16; ++q) e += partB[q][g][i];
            e += bitsf[rr][side] * win0r + dly[rr][side] * win1r;
            const float v = tanhf(e);
            __hip_atomic_store(
                &ws[(size_t)sb_w * (BATCH * 512) + (size_t)(r0 + rr) * 512 + side * 256 + scol0 + sc],
                v, __ATOMIC_RELAXED, __HIP_MEMORY_SCOPE_AGENT);
        }
        __syncthreads();   /* drains all state/ring stores before publish */
        if (tid == 0)
            __hip_atomic_fetch_add(&ctrline[cs], 1u, __ATOMIC_RELEASE,
                                   __HIP_MEMORY_SCOPE_AGENT);
    }

    /* ---- tail: sign outputs for t-2 = 510, 511 (cs0 only) ---- */
    if (cs == 0) {
        if (tid < CS) {
            long guard = 0;
            while (__hip_atomic_load(&ctrline[tid], __ATOMIC_RELAXED,
                                     __HIP_MEMORY_SCOPE_AGENT) < (unsigned)TSTEPS) {
                __builtin_amdgcn_s_sleep(8);
                if (++guard > 300000L) break;
            }
            (void)__hip_atomic_load(&ctrline[tid], __ATOMIC_ACQUIRE,
                                    __HIP_MEMORY_SCOPE_AGENT);
        }
        __syncthreads();
        if (tid >= 16 && tid < 32) {
            const int r = (tid - 16) >> 1, j = tid & 1;
            for (int tt = TSTEPS; tt < TSTEPS + 2; ++tt) {
                float s = bout[j];
                #pragma unroll
                for (int q = 0; q < CS; ++q)
                    s += __hip_atomic_load(
                        &ring[((((size_t)((tt + 2) & 3)) * NTEAM + team) * CS + q) * 16 + r * 2 + j],
                        __ATOMIC_RELAXED, __HIP_MEMORY_SCOPE_AGENT);
                const float sg = (s > 0.f) ? 1.f : ((s < 0.f) ? -1.f : 0.f);
                (j ? out1 : out0)[(size_t)(r0 + r) * TOUT + (tt - 2 - WASH)] = sg;
            }
        }
    }
}

extern "C" void kernel_launch(void* const* d_in, const int* in_sizes, int n_in,
                              void* d_out, int out_size, void* d_ws, size_t ws_size,
                              hipStream_t stream) {
    (void)in_sizes; (void)n_in; (void)ws_size; (void)out_size;
    float* ws = (float*)d_ws;
    hipLaunchKernelGGL(init_kernel, dim3(128), dim3(256), 0, stream, ws);

    const int*   settings = (const int*)d_in[0];
    const float* noiseA   = (const float*)d_in[1];
    const float* noiseB   = (const float*)d_in[2];
    const float* WinA     = (const float*)d_in[3];
    const float* WrecA    = (const float*)d_in[4];
    const float* WinB     = (const float*)d_in[5];
    const float* WrecB    = (const float*)d_in[6];
    const float* Wx       = (const float*)d_in[7];   /* d_in[8] = Wh unused (h0 == 0) */
    const float* bg       = (const float*)d_in[9];
    const float* Wout     = (const float*)d_in[10];
    const float* bout     = (const float*)d_in[11];
    float*       outp     = (float*)d_out;

    void* args[] = { &settings, &noiseA, &noiseB, &WinA, &WrecA, &WinB, &WrecB,
                     &Wx, &bg, &Wout, &bout, &outp, &ws };
    hipLaunchCooperativeKernel((void*)loop_kernel, dim3(NBLK), dim3(NT),
                               args, 0, stream);
}

// Round 7
// 8670.007 us; speedup vs baseline: 1.3876x; 1.3876x over previous
//
#include <hip/hip_runtime.h>
#include <cmath>

#define BATCH 256
#define TSTEPS 512
#define NDIM 256
#define WASH 64
#define TOUT (TSTEPS - WASH)   /* 448 */
#define NB 8                   /* batch rows per team */
#define CS 8                   /* column-split blocks per team */
#define NTEAM 32
#define NBLK 256
#define NT 1024

/* ---- per-XCD exchange region (floats), indexed by PHYSICAL XCD id ---- */
#define XR_SB   0                          /* state [3][4][8][512] = 49152 */
#define XR_RING 49152                      /* logit partials [4][4][8][16] = 2048 */
#define XR_FLAG (49152 + 2048)             /* int flags [4 teams][16] = 64 */
#define XR_SIZE 51264                      /* 128B-aligned stride */
#define GCTR_OFF (8 * XR_SIZE)             /* [0]=global barrier, [8+x]=xcd slot ctr */

__global__ void init_kernel(float* ws) {
    /* only the tiny agent-scope counters need per-launch reset; per-XCD
       regions are self-initialized inside the main kernel (same-L2 writes) */
    if (threadIdx.x < 32)
        __hip_atomic_store((unsigned*)(ws + GCTR_OFF) + threadIdx.x, 0u,
                           __ATOMIC_RELAXED, __HIP_MEMORY_SCOPE_AGENT);
}

__global__ void __launch_bounds__(NT, 4)
loop_kernel(const int* __restrict__ settings, const float* __restrict__ noiseA,
            const float* __restrict__ noiseB, const float* __restrict__ WinA,
            const float* __restrict__ WrecA, const float* __restrict__ WinB,
            const float* __restrict__ WrecB, const float* __restrict__ Wx,
            const float* __restrict__ bg, const float* __restrict__ Wout,
            const float* __restrict__ bout, float* __restrict__ out, float* ws)
{
    __shared__ float xbuf[516][8];    /* x transposed [k][row], sub-block swizzled */
    __shared__ float sT[512][8];      /* raw state transposed, same swizzle */
    __shared__ float partA[16][64][9];
    __shared__ float partB[16][64][9];
    __shared__ float hzT[32][9];
    __shared__ float hnT[32][9];
    __shared__ float bitsf[8][2];
    __shared__ float dly[8][2];
    __shared__ int   s_xcd, s_slot;

    const int tid = threadIdx.x;

    /* ---- dynamic same-XCD team formation (placement-independent) ---- */
    if (tid == 0) {
        /* HW_REG_XCC_ID (id=20), offset 0, size 4: imm = 20 | (3<<11) */
        const int xcd = (int)(__builtin_amdgcn_s_getreg(20 | (3 << 11)) & 7);
        const unsigned slot = __hip_atomic_fetch_add(
            (unsigned*)(ws + GCTR_OFF) + 8 + xcd, 1u,
            __ATOMIC_RELAXED, __HIP_MEMORY_SCOPE_AGENT);
        s_xcd = xcd; s_slot = (int)(slot & 31);
    }
    __syncthreads();
    const int xcd  = s_xcd;
    const int slot = s_slot;
    const int tl   = slot >> 3;          /* team-local id on this XCD: 0..3 */
    const int cs   = slot & 7;           /* column-split role: 0..7 */
    const int team = xcd * 4 + tl;       /* global team: 0..31 */
    const int r0   = team * NB;

    float* xreg  = ws + (size_t)xcd * XR_SIZE;
    float* xsb   = xreg + XR_SB;
    float* xring = xreg + XR_RING;
    volatile int* xflag = (volatile int*)(xreg + XR_FLAG);

    /* ---- self-init own share of the per-XCD region (plain L2-local stores) */
    for (int i = tid; i < 3 * 8 * 64; i += NT) {       /* own 64 state cols, 3 slots */
        const int sl = i >> 9, rem = i & 511, row = rem >> 6, col = rem & 63;
        xsb[((size_t)(sl * 4 + tl) * 8 + row) * 512 + cs * 64 + col] = 0.f;
    }
    for (int i = tid; i < 4 * 16; i += NT)             /* own ring entries, 4 slots */
        xring[((size_t)((i >> 4) * 4 + tl) * 8 + cs) * 16 + (i & 15)] = 0.f;
    if (tid == 0) xflag[tl * 16 + cs] = 0;
    asm volatile("s_waitcnt vmcnt(0)" ::: "memory");
    __syncthreads();

    /* ---- one agent-scope startup barrier (all zeroing done) ---- */
    if (tid == 0) {
        unsigned* g = (unsigned*)(ws + GCTR_OFF);
        __hip_atomic_fetch_add(g, 1u, __ATOMIC_RELEASE, __HIP_MEMORY_SCOPE_AGENT);
        long guard = 0;
        while (__hip_atomic_load(g, __ATOMIC_RELAXED, __HIP_MEMORY_SCOPE_AGENT) < NBLK) {
            __builtin_amdgcn_s_sleep(2);
            if (++guard > 100000000L) break;
        }
        (void)__hip_atomic_load(g, __ATOMIC_ACQUIRE, __HIP_MEMORY_SCOPE_AGENT);
    }
    __syncthreads();

    /* ---- GEMM mapping: tid = kq*64 + rh*32 + c2 ---- */
    const int kq = tid >> 6;
    const int rh = (tid >> 5) & 1;
    const int c2 = tid & 31;
    const float* wxp0 = Wx + ((c2 < 16) ? (cs * 32 + 2 * c2)
                                        : (512 + cs * 32 + 2 * (c2 - 16)));
    const int side  = cs >> 2;               /* 0 = A, 1 = B */
    const int scol0 = (cs & 3) * 64;
    const float* wrp0 = (side ? WrecB : WrecA) + (scol0 + 2 * c2);
    const float* wins = side ? WinB : WinA;

    float2 w_s[16];                          /* register-resident Wrec slice */
    #pragma unroll
    for (int k = 0; k < 16; ++k)
        w_s[k] = *(const float2*)(wrp0 + (size_t)(kq * 16 + k) * 256);

    const int xk = tid & 511;
    const int xh = tid >> 9;

    float biasg = 0.f, win0r = 0.f, win1r = 0.f;
    if (tid < 512) {
        const int oc = tid & 63;
        biasg = bg[(oc < 32) ? (cs * 32 + oc) : (512 + cs * 32 + (oc - 32))];
        win0r = wins[scol0 + oc];
        win1r = wins[NDIM + scol0 + oc];
    }
    const int lane = tid & 63;
    const int wv = tid >> 6;
    const int lr = wv >> 1, lj = wv & 1;
    const float woreg = (lane < 32) ? Wout[(cs * 32 + lane) * 2 + lj] : 0.f;

    float* out0 = out;
    float* out1 = out + (size_t)BATCH * TOUT;
    float* out2 = out + (size_t)2 * BATCH * TOUT;

    for (int t = 0; t < TSTEPS; ++t) {
        const int sb_r = t % 3, sb_w = (t + 1) % 3;

        /* ---- P0a: nontemporal noise prefetch (keeps weights L2-resident) ---- */
        float nz[4];
        {
            const float* np_ = (xk < 256)
                ? (noiseA + (size_t)r0 * TSTEPS * NDIM + (size_t)t * NDIM + xk)
                : (noiseB + (size_t)r0 * TSTEPS * NDIM + (size_t)t * NDIM + (xk - 256));
            #pragma unroll
            for (int q = 0; q < 4; ++q)
                nz[q] = __builtin_nontemporal_load(np_ + (size_t)(xh * 4 + q) * TSTEPS * NDIM);
        }
        if (tid >= 16 && tid < 32) {          /* delayed-logit reduce: ring(t-2) made
                                                 L2-visible by the PREVIOUS step's wait */
            const int r = (tid - 16) >> 1, j = tid & 1;
            float s = (t >= 2) ? bout[j] : 0.f;
            #pragma unroll
            for (int q = 0; q < CS; ++q)
                s += ((volatile float*)xring)[((size_t)(((t + 2) & 3) * 4 + tl) * 8 + q) * 16 + r * 2 + j];
            dly[r][j] = s;
            if (cs == 0 && t - 2 >= WASH) {
                const float sg = (s > 0.f) ? 1.f : ((s < 0.f) ? -1.f : 0.f);
                (j ? out1 : out0)[(size_t)(r0 + r) * TOUT + (t - 2 - WASH)] = sg;
            }
        } else if (tid < 16) {                /* bits + spins (+ out2 by cs0) */
            const int r = tid >> 1, j = tid & 1;
            const float bit = (float)settings[((size_t)(r0 + r) * TSTEPS + t) * 2 + j];
            bitsf[r][j] = bit;
            xbuf[512 + j][r] = 2.f * bit - 1.f;
            if (cs == 0 && t >= WASH)
                out2[((size_t)(r0 + r) * TOUT + (t - WASH)) * 2 + j] = bit;
        }

        /* ---- P0b: wave-0 polls the team flag line in LOCAL L2 (volatile=sc0) ---- */
        if (t > 0 && wv == 0 && lane < CS) {
            volatile int* fl = &xflag[tl * 16 + lane];
            long guard = 0;
            while (*fl < t) {
                __builtin_amdgcn_s_sleep(1);
                if (++guard > 4000000L) break;   /* hang insurance */
            }
        }
        __syncthreads();

        /* ---- P0c: state gather from local L2 (volatile, L1-bypassing) ---- */
        {
            const volatile float* srow = xsb + (size_t)(sb_r * 4 + tl) * 8 * 512 + xk;
            float u[4], v[4];
            #pragma unroll
            for (int q = 0; q < 4; ++q) {
                u[q] = srow[(size_t)(xh * 4 + q) * 512];
                v[q] = u[q] + nz[q];
            }
            const int sw = 4 * (xh ^ ((xk >> 2) & 1));
            *(float4*)&xbuf[xk][sw] = make_float4(v[0], v[1], v[2], v[3]);
            *(float4*)&sT[xk][sw]   = make_float4(u[0], u[1], u[2], u[3]);
        }
        __syncthreads();

        /* ---- P1: Gp -> partA, Sp -> partB ---- */
        {
            const int kbeg = kq * 32;
            const int kend = (kq == 15) ? 514 : (kbeg + 32);
            float a00=0,a01=0,a10=0,a11=0,a20=0,a21=0,a30=0,a31=0;
            const float* wp = wxp0 + (size_t)kbeg * 768;
            #pragma unroll 4
            for (int k = kbeg; k < kend; ++k, wp += 768) {
                const float2 w  = *(const float2*)wp;
                const float4 xv = *(const float4*)&xbuf[k][4 * (rh ^ ((k >> 2) & 1))];
                a00 = fmaf(xv.x, w.x, a00); a01 = fmaf(xv.x, w.y, a01);
                a10 = fmaf(xv.y, w.x, a10); a11 = fmaf(xv.y, w.y, a11);
                a20 = fmaf(xv.z, w.x, a20); a21 = fmaf(xv.z, w.y, a21);
                a30 = fmaf(xv.w, w.x, a30); a31 = fmaf(xv.w, w.y, a31);
            }
            float* pb = &partA[kq][rh * 32 + c2][0];
            pb[0] = a00; pb[1] = a10; pb[2] = a20; pb[3] = a30;
            pb[4] = a01; pb[5] = a11; pb[6] = a21; pb[7] = a31;
        }
        {
            const int kb = kq * 16;
            float a00=0,a01=0,a10=0,a11=0,a20=0,a21=0,a30=0,a31=0;
            #pragma unroll
            for (int k = 0; k < 16; ++k) {
                const float2 w = w_s[k];
                const int k2 = side * 256 + kb + k;
                const float4 sv = *(const float4*)&sT[k2][4 * (rh ^ ((k2 >> 2) & 1))];
                a00 = fmaf(sv.x, w.x, a00); a01 = fmaf(sv.x, w.y, a01);
                a10 = fmaf(sv.y, w.x, a10); a11 = fmaf(sv.y, w.y, a11);
                a20 = fmaf(sv.z, w.x, a20); a21 = fmaf(sv.z, w.y, a21);
                a30 = fmaf(sv.w, w.x, a30); a31 = fmaf(sv.w, w.y, a31);
            }
            float* pb = &partB[kq][rh * 32 + c2][0];
            pb[0] = a00; pb[1] = a10; pb[2] = a20; pb[3] = a30;
            pb[4] = a01; pb[5] = a11; pb[6] = a21; pb[7] = a31;
        }
        __syncthreads();

        /* ---- P2: Gr reduce + activation ---- */
        if (tid < 512) {
            const int rr = tid >> 6, oc = tid & 63;
            const int g = (rr >> 2) * 32 + (oc >> 1);
            const int i = (oc & 1) * 4 + (rr & 3);
            float e = biasg;
            #pragma unroll
            for (int q = 0; q < 16; ++q) e += partA[q][g][i];
            if (oc < 32) hzT[oc][rr] = 1.f / (1.f + expf(-e));
            else         hnT[oc - 32][rr] = tanhf(e);
        }
        __syncthreads();

        /* ---- P3: logit partial + Sr (plain L2-local stores) ---- */
        {
            float pl = 0.f;
            if (lane < 32)
                pl = (1.f - hzT[lane][lr]) * hnT[lane][lr] * woreg;
            #pragma unroll
            for (int s = 16; s; s >>= 1) pl += __shfl_down(pl, s, 64);
            if (lane == 0)
                xring[((size_t)((t & 3) * 4 + tl) * 8 + cs) * 16 + wv] = pl;
        }
        if (tid < 512) {
            const int rr = tid >> 6, sc = tid & 63;
            const int g = (rr >> 2) * 32 + (sc >> 1);
            const int i = (sc & 1) * 4 + (rr & 3);
            float e = 0.f;
            #pragma unroll
            for (int q = 0; q < 16; ++q) e += partB[q][g][i];
            e += bitsf[rr][side] * win0r + dly[rr][side] * win1r;
            xsb[((size_t)(sb_w * 4 + tl) * 8 + rr) * 512 + side * 256 + scol0 + sc] = tanhf(e);
        }
        /* every wave drains its stores to L2, then one volatile flag publish */
        asm volatile("s_waitcnt vmcnt(0)" ::: "memory");
        __syncthreads();
        if (tid == 0) xflag[tl * 16 + cs] = t + 1;
    }

    /* ---- tail: sign outputs for t-2 = 510, 511 (role-0 blocks only) ---- */
    if (cs == 0) {
        if (tid < CS) {
            volatile int* fl = &xflag[tl * 16 + tid];
            long guard = 0;
            while (*fl < TSTEPS) {
                __builtin_amdgcn_s_sleep(1);
                if (++guard > 4000000L) break;
            }
        }
        __syncthreads();
        if (tid >= 16 && tid < 32) {
            const int r = (tid - 16) >> 1, j = tid & 1;
            for (int tt = TSTEPS; tt < TSTEPS + 2; ++tt) {
                float s = bout[j];
                #pragma unroll
                for (int q = 0; q < CS; ++q)
                    s += ((volatile float*)xring)[((size_t)(((tt + 2) & 3) * 4 + tl) * 8 + q) * 16 + r * 2 + j];
                const float sg = (s > 0.f) ? 1.f : ((s < 0.f) ? -1.f : 0.f);
                (j ? out1 : out0)[(size_t)(r0 + r) * TOUT + (tt - 2 - WASH)] = sg;
            }
        }
    }
}

extern "C" void kernel_launch(void* const* d_in, const int* in_sizes, int n_in,
                              void* d_out, int out_size, void* d_ws, size_t ws_size,
                              hipStream_t stream) {
    (void)in_sizes; (void)n_in; (void)ws_size; (void)out_size;
    float* ws = (float*)d_ws;
    hipLaunchKernelGGL(init_kernel, dim3(1), dim3(64), 0, stream, ws);

    const int*   settings = (const int*)d_in[0];
    const float* noiseA   = (const float*)d_in[1];
    const float* noiseB   = (const float*)d_in[2];
    const float* WinA     = (const float*)d_in[3];
    const float* WrecA    = (const float*)d_in[4];
    const float* WinB     = (const float*)d_in[5];
    const float* WrecB    = (const float*)d_in[6];
    const float* Wx       = (const float*)d_in[7];   /* d_in[8] = Wh unused (h0 == 0) */
    const float* bg       = (const float*)d_in[9];
    const float* Wout     = (const float*)d_in[10];
    const float* bout     = (const float*)d_in[11];
    float*       outp     = (float*)d_out;

    void* args[] = { &settings, &noiseA, &noiseB, &WinA, &WrecA, &WinB, &WrecB,
                     &Wx, &bg, &Wout, &bout, &outp, &ws };
    hipLaunchCooperativeKernel((void*)loop_kernel, dim3(NBLK), dim3(NT),
                               args, 0, stream);
}